// Round 20
// baseline (218.261 us; speedup 1.0000x reference)
//
#include <hip/hip_runtime.h>
#include <hip/hip_bf16.h>
#include <cstdint>
#include <cstddef>

#define D_MODEL 768
#define D_STATE 16
#define BB      4
#define LL      2048
#define M_TOT   (BB*LL)      // 8192
#define NCHUNK  64
#define LCH     (LL/NCHUNK)  // 32
#define N_DBC   896          // 768 delta + 16 B + 16 C + 96 pad
#define KC      768          // all GEMMs share K = D_MODEL
#define BK      64           // k-elements per staged step
#define NT2     (KC/BK)      // 12 K-steps (even)

typedef __attribute__((ext_vector_type(8))) short bf16x8;
typedef __attribute__((ext_vector_type(4))) float f32x4;

__device__ __forceinline__ float clampf_(float x, float lo, float hi) {
    return fminf(fmaxf(x, lo), hi);
}
__device__ __forceinline__ float siluf_(float x) {
    return x / (1.f + __expf(-x));
}
// f32 -> bf16 round-to-nearest-even, as raw u16
__device__ __forceinline__ unsigned short f2bf(float f) {
    unsigned u = __float_as_uint(f);
    u += 0x7fffu + ((u >> 16) & 1u);
    return (unsigned short)(u >> 16);
}
__device__ __forceinline__ float bf2f(unsigned short u) {
    return __uint_as_float(((unsigned)u) << 16);
}
// pack 8 f32 (two float4) -> 8 bf16 as a float4 bit-image
__device__ __forceinline__ float4 packbf8(float4 lo, float4 hi) {
    union { float4 f; unsigned short s[8]; } u;
    u.s[0] = f2bf(lo.x); u.s[1] = f2bf(lo.y); u.s[2] = f2bf(lo.z); u.s[3] = f2bf(lo.w);
    u.s[4] = f2bf(hi.x); u.s[5] = f2bf(hi.y); u.s[6] = f2bf(hi.z); u.s[7] = f2bf(hi.w);
    return u.f;
}

// ---------------- prep kernels ----------------

__global__ __launch_bounds__(256) void k_prep_A(const float* __restrict__ A_log,
                                                float* __restrict__ A_cl, int n) {
    int i = blockIdx.x * 256 + threadIdx.x;
    if (i < n) A_cl[i] = clampf_(-__expf(A_log[i]), -5.f, -0.1f);
}

// transpose R x C f32 -> C x R bf16 (R,C multiples of 32); dst row stride = R
__global__ __launch_bounds__(256) void k_transpose_bf16(const float* __restrict__ src,
                                                        unsigned short* __restrict__ dst,
                                                        int R, int C) {
    __shared__ float tile[32][33];
    int tx = threadIdx.x & 31, ty = threadIdx.x >> 5;
    int c0 = blockIdx.x * 32, r0 = blockIdx.y * 32;
    #pragma unroll
    for (int rr = ty; rr < 32; rr += 8)
        tile[rr][tx] = src[(size_t)(r0 + rr) * C + c0 + tx];
    __syncthreads();
    #pragma unroll
    for (int rr = ty; rr < 32; rr += 8)
        dst[(size_t)(c0 + rr) * R + r0 + tx] = f2bf(tile[tx][rr]);
}

// rows 768..895 of WdBC: W_B^T, W_C^T, zero-pad
__global__ __launch_bounds__(256) void k_fill_bc(const float* __restrict__ W_B,
                                                 const float* __restrict__ W_C,
                                                 unsigned short* __restrict__ WdBC) {
    int idx = blockIdx.x * 256 + threadIdx.x;     // 128*768
    if (idx >= 128 * D_MODEL) return;
    int r = idx / D_MODEL + D_MODEL, k = idx % D_MODEL;
    unsigned short v = 0;
    if (r < D_MODEL + 16)       v = f2bf(W_B[k * 16 + (r - D_MODEL)]);
    else if (r < D_MODEL + 32)  v = f2bf(W_C[k * 16 + (r - D_MODEL - 16)]);
    WdBC[(size_t)r * D_MODEL + k] = v;
}

__global__ __launch_bounds__(256) void k_bias_dbc(const float* __restrict__ b_delta,
                                                  const float* __restrict__ b_B,
                                                  const float* __restrict__ b_C,
                                                  float* __restrict__ bias) {
    int i = blockIdx.x * 256 + threadIdx.x;
    if (i >= N_DBC) return;
    float v = 0.f;
    if (i < D_MODEL)            v = b_delta[i];
    else if (i < D_MODEL + 16)  v = b_B[i - D_MODEL];
    else if (i < D_MODEL + 32)  v = b_C[i - D_MODEL - 16];
    bias[i] = v;
}

// ---------------- main bf16 MFMA GEMM ----------------
// 128x128 tile, 4 waves, BK=64 (12 K-steps), reg-staged, 2 LDS buffers
// (64KB), ONE barrier per K-step, XOR swizzle slot = jl ^ (row&7), named
// scalar staging (rule #20). EPI 0 reads A as f32 (raw x) and converts to
// bf16 in-register during staging (k_convert_x fused away).
template<int EPI>
__global__ __launch_bounds__(256, 2) void k_gemm(const void* __restrict__ Avoid,
                                              const unsigned short* __restrict__ Bt,
                                              const float* __restrict__ bias,
                                              int gx,
                                              float* __restrict__ out_f,
                                              float* __restrict__ out_f2,
                                              unsigned short* __restrict__ out_b0,
                                              unsigned short* __restrict__ out_b1) {
    __shared__ __align__(16) unsigned short As0[128 * 64], As1[128 * 64];
    __shared__ __align__(16) unsigned short Bs0[128 * 64], Bs1[128 * 64];
    const int tid = threadIdx.x;
    const int wave = tid >> 6, lane = tid & 63;
    const int wm = wave >> 1, wn = wave & 1;
    const int lr = lane & 15;

    // bijective XCD swizzle (m204, r==0 case); all grids here are %8==0
    const int nwg = gridDim.x;
    const int wg = blockIdx.x;
    int swz = wg;
    if ((nwg & 7) == 0) {
        const int q = nwg >> 3;
        swz = (wg & 7) * q + (wg >> 3);
    }
    const int bx = swz % gx, by = swz / gx;
    const int m0 = by * 128, n0 = bx * 128;

    // staging: 128x64 tile = 1024 chunks of 8 shorts; thread owns chunks
    // c = g*256 + tid, g=0..3: row = c>>3, jl = c&7, slot = jl ^ (row&7).
    const int row0 = tid >> 3, jl = tid & 7;
    const int r0_ = row0,      r1_ = row0 + 32,  r2_ = row0 + 64,  r3_ = row0 + 96;
    const unsigned short* Abf = (const unsigned short*)Avoid;  // EPI 1,2
    const float*          Af  = (const float*)Avoid;           // EPI 0
    const unsigned short* gA0 = &Abf[(size_t)(m0 + r0_) * KC + jl * 8];
    const unsigned short* gA1 = &Abf[(size_t)(m0 + r1_) * KC + jl * 8];
    const unsigned short* gA2 = &Abf[(size_t)(m0 + r2_) * KC + jl * 8];
    const unsigned short* gA3 = &Abf[(size_t)(m0 + r3_) * KC + jl * 8];
    const float* fA0 = &Af[(size_t)(m0 + r0_) * KC + jl * 8];
    const float* fA1 = &Af[(size_t)(m0 + r1_) * KC + jl * 8];
    const float* fA2 = &Af[(size_t)(m0 + r2_) * KC + jl * 8];
    const float* fA3 = &Af[(size_t)(m0 + r3_) * KC + jl * 8];
    const unsigned short* gB0 = &Bt[(size_t)(n0 + r0_) * KC + jl * 8];
    const unsigned short* gB1 = &Bt[(size_t)(n0 + r1_) * KC + jl * 8];
    const unsigned short* gB2 = &Bt[(size_t)(n0 + r2_) * KC + jl * 8];
    const unsigned short* gB3 = &Bt[(size_t)(n0 + r3_) * KC + jl * 8];
    const int w0_ = r0_ * 64 + (jl ^ (r0_ & 7)) * 8;
    const int w1_ = r1_ * 64 + (jl ^ (r1_ & 7)) * 8;
    const int w2_ = r2_ * 64 + (jl ^ (r2_ & 7)) * 8;
    const int w3_ = r3_ * 64 + (jl ^ (r3_ & 7)) * 8;

    f32x4 acc[4][4] = {};
    float4 ra0, ra1, ra2, ra3, rb0, rb1, rb2, rb3;
    float4 qa0, qa1, qa2, qa3;   // hi-halves for EPI 0 f32 loads

    auto loadT = [&](int kt) {
        if (EPI == 0) {
            ra0 = *(const float4*)(fA0 + kt); qa0 = *(const float4*)(fA0 + kt + 4);
            ra1 = *(const float4*)(fA1 + kt); qa1 = *(const float4*)(fA1 + kt + 4);
            ra2 = *(const float4*)(fA2 + kt); qa2 = *(const float4*)(fA2 + kt + 4);
            ra3 = *(const float4*)(fA3 + kt); qa3 = *(const float4*)(fA3 + kt + 4);
        } else {
            ra0 = *(const float4*)(gA0 + kt);
            ra1 = *(const float4*)(gA1 + kt);
            ra2 = *(const float4*)(gA2 + kt);
            ra3 = *(const float4*)(gA3 + kt);
        }
        rb0 = *(const float4*)(gB0 + kt);
        rb1 = *(const float4*)(gB1 + kt);
        rb2 = *(const float4*)(gB2 + kt);
        rb3 = *(const float4*)(gB3 + kt);
    };
    auto writeT = [&](unsigned short* Ab, unsigned short* Bb) {
        if (EPI == 0) {
            *(float4*)&Ab[w0_] = packbf8(ra0, qa0);
            *(float4*)&Ab[w1_] = packbf8(ra1, qa1);
            *(float4*)&Ab[w2_] = packbf8(ra2, qa2);
            *(float4*)&Ab[w3_] = packbf8(ra3, qa3);
        } else {
            *(float4*)&Ab[w0_] = ra0;
            *(float4*)&Ab[w1_] = ra1;
            *(float4*)&Ab[w2_] = ra2;
            *(float4*)&Ab[w3_] = ra3;
        }
        *(float4*)&Bb[w0_] = rb0;
        *(float4*)&Bb[w1_] = rb1;
        *(float4*)&Bb[w2_] = rb2;
        *(float4*)&Bb[w3_] = rb3;
    };
    auto computeT = [&](const unsigned short* Ab, const unsigned short* Bb) {
        #pragma unroll
        for (int kh = 0; kh < 2; ++kh) {
            const int so = ((kh * 4 + (lane >> 4)) ^ (lr & 7)) * 8;  // swizzled k-slot
            bf16x8 af0 = *(const bf16x8*)&Ab[(wm * 64 +  0 + lr) * 64 + so];
            bf16x8 af1 = *(const bf16x8*)&Ab[(wm * 64 + 16 + lr) * 64 + so];
            bf16x8 af2 = *(const bf16x8*)&Ab[(wm * 64 + 32 + lr) * 64 + so];
            bf16x8 af3 = *(const bf16x8*)&Ab[(wm * 64 + 48 + lr) * 64 + so];
            bf16x8 bf0 = *(const bf16x8*)&Bb[(wn * 64 +  0 + lr) * 64 + so];
            bf16x8 bf1 = *(const bf16x8*)&Bb[(wn * 64 + 16 + lr) * 64 + so];
            bf16x8 bf2 = *(const bf16x8*)&Bb[(wn * 64 + 32 + lr) * 64 + so];
            bf16x8 bf3 = *(const bf16x8*)&Bb[(wn * 64 + 48 + lr) * 64 + so];
            acc[0][0] = __builtin_amdgcn_mfma_f32_16x16x32_bf16(af0, bf0, acc[0][0], 0, 0, 0);
            acc[0][1] = __builtin_amdgcn_mfma_f32_16x16x32_bf16(af0, bf1, acc[0][1], 0, 0, 0);
            acc[0][2] = __builtin_amdgcn_mfma_f32_16x16x32_bf16(af0, bf2, acc[0][2], 0, 0, 0);
            acc[0][3] = __builtin_amdgcn_mfma_f32_16x16x32_bf16(af0, bf3, acc[0][3], 0, 0, 0);
            acc[1][0] = __builtin_amdgcn_mfma_f32_16x16x32_bf16(af1, bf0, acc[1][0], 0, 0, 0);
            acc[1][1] = __builtin_amdgcn_mfma_f32_16x16x32_bf16(af1, bf1, acc[1][1], 0, 0, 0);
            acc[1][2] = __builtin_amdgcn_mfma_f32_16x16x32_bf16(af1, bf2, acc[1][2], 0, 0, 0);
            acc[1][3] = __builtin_amdgcn_mfma_f32_16x16x32_bf16(af1, bf3, acc[1][3], 0, 0, 0);
            acc[2][0] = __builtin_amdgcn_mfma_f32_16x16x32_bf16(af2, bf0, acc[2][0], 0, 0, 0);
            acc[2][1] = __builtin_amdgcn_mfma_f32_16x16x32_bf16(af2, bf1, acc[2][1], 0, 0, 0);
            acc[2][2] = __builtin_amdgcn_mfma_f32_16x16x32_bf16(af2, bf2, acc[2][2], 0, 0, 0);
            acc[2][3] = __builtin_amdgcn_mfma_f32_16x16x32_bf16(af2, bf3, acc[2][3], 0, 0, 0);
            acc[3][0] = __builtin_amdgcn_mfma_f32_16x16x32_bf16(af3, bf0, acc[3][0], 0, 0, 0);
            acc[3][1] = __builtin_amdgcn_mfma_f32_16x16x32_bf16(af3, bf1, acc[3][1], 0, 0, 0);
            acc[3][2] = __builtin_amdgcn_mfma_f32_16x16x32_bf16(af3, bf2, acc[3][2], 0, 0, 0);
            acc[3][3] = __builtin_amdgcn_mfma_f32_16x16x32_bf16(af3, bf3, acc[3][3], 0, 0, 0);
        }
    };

    // prologue: tiles 0 and 1 into buf0/buf1 (compiler inserts vmcnt waits)
    loadT(0);
    writeT(As0, Bs0);
    loadT(BK);
    writeT(As1, Bs1);
    asm volatile("s_waitcnt lgkmcnt(0)" ::: "memory");
    __builtin_amdgcn_sched_barrier(0);
    __builtin_amdgcn_s_barrier();
    __builtin_amdgcn_sched_barrier(0);

#define SUBSTEP(Ab, Bb, t) do {                                   \
        if ((t) + 2 < NT2) loadT(((t) + 2) * BK);                 \
        computeT(Ab, Bb);                                         \
        asm volatile("s_waitcnt lgkmcnt(0)" ::: "memory");        \
        __builtin_amdgcn_sched_barrier(0);                        \
        __builtin_amdgcn_s_barrier();                             \
        __builtin_amdgcn_sched_barrier(0);                        \
        if ((t) + 2 < NT2) writeT(Ab, Bb);                        \
    } while (0)

    for (int t = 0; t < NT2; t += 2) {
        SUBSTEP(As0, Bs0, t);
        SUBSTEP(As1, Bs1, t + 1);
    }
#undef SUBSTEP

    #pragma unroll
    for (int mt = 0; mt < 4; ++mt) {
        int row = m0 + wm * 64 + mt * 16 + (lane >> 4) * 4;
        #pragma unroll
        for (int nt = 0; nt < 4; ++nt) {
            int col = n0 + wn * 64 + nt * 16 + lr;
            #pragma unroll
            for (int i = 0; i < 4; ++i) {
                int r = row + i;
                float v = acc[mt][nt][i] + bias[col];
                if (EPI == 0) {
                    float s = siluf_(v);
                    if (col < D_MODEL) out_b0[(size_t)r * D_MODEL + col] = f2bf(s);
                    else               out_b1[(size_t)r * D_MODEL + (col - D_MODEL)] = f2bf(s);
                } else if (EPI == 1) {
                    if (col < D_MODEL) {
                        float sp = (v > 20.f) ? v : log1pf(__expf(v));
                        out_b0[(size_t)r * D_MODEL + col] = f2bf(clampf_(sp + 1e-4f, 1e-4f, 1.f));
                    } else if (col < D_MODEL + 16) {
                        out_f[(size_t)r * D_STATE + (col - D_MODEL)] = v;
                    } else if (col < D_MODEL + 32) {
                        out_f2[(size_t)r * D_STATE + (col - D_MODEL - 16)] = v;
                    }
                } else {
                    out_f[(size_t)r * D_MODEL + col] = clampf_(v, -10.f, 10.f);
                }
            }
        }
    }
}

// ---------------- chunked selective scan ----------------
// pass A: per (b, chunk, d) local scan from h=0; emit h_end, Aprod
__global__ __launch_bounds__(256) void k_scanA(const unsigned short* __restrict__ dlt,
                                               const unsigned short* __restrict__ xm,
                                               const float* __restrict__ Bm,
                                               const float* __restrict__ A_cl,
                                               float* __restrict__ h_end,
                                               float* __restrict__ Aprod) {
    const int d = blockIdx.x * 256 + threadIdx.x;
    const int c = blockIdx.y, b = blockIdx.z;
    __shared__ float Bsh[LCH][D_STATE];
    const int rowbase = b * LL + c * LCH;
    for (int i = threadIdx.x; i < LCH * D_STATE; i += 256)
        ((float*)Bsh)[i] = Bm[(size_t)rowbase * D_STATE + i];
    __syncthreads();

    float Asv[16], h[16], ap[16];
    #pragma unroll
    for (int s = 0; s < 16; ++s) {
        Asv[s] = A_cl[s * D_MODEL + d];
        h[s] = 0.f; ap[s] = 1.f;
    }
    for (int tt = 0; tt < LCH; ++tt) {
        const size_t rowoff = (size_t)(rowbase + tt);
        float dltv = bf2f(dlt[rowoff * D_MODEL + d]);
        float xv   = bf2f(xm [rowoff * D_MODEL + d]);
        float dx = dltv * xv;
        #pragma unroll
        for (int s = 0; s < 16; ++s) {
            float dA  = __expf(fmaxf(dltv * Asv[s], -2.f));
            float dBu = clampf_(dx * Bsh[tt][s], -5.f, 5.f);
            h[s] = clampf_(fmaf(dA, h[s], dBu), -100.f, 100.f);
            ap[s] *= dA;
        }
    }
    const size_t off = (((size_t)b * NCHUNK + c) * D_STATE) * D_MODEL + d;
    #pragma unroll
    for (int s = 0; s < 16; ++s) {
        h_end[off + (size_t)s * D_MODEL] = h[s];
        Aprod[off + (size_t)s * D_MODEL] = ap[s];
    }
}

// pass B: carry propagation across chunks per (b,s,d)
__global__ __launch_bounds__(256) void k_scanB(const float* __restrict__ h_end,
                                               const float* __restrict__ Aprod,
                                               float* __restrict__ h_in) {
    const int idx = blockIdx.x * 256 + threadIdx.x;  // 4*16*768 = 49152
    const int d = idx % D_MODEL;
    const int rest = idx / D_MODEL;
    const int s = rest & 15, b = rest >> 4;
    float hc = 0.f;
    for (int c = 0; c < NCHUNK; ++c) {
        const size_t off = (((size_t)b * NCHUNK + c) * D_STATE + s) * D_MODEL + d;
        h_in[off] = hc;
        hc = Aprod[off] * hc + h_end[off];
    }
}

// pass C: replay with true carry, fuse y = clip(sum_s h*C) + xm*D, * gate -> bf16
__global__ __launch_bounds__(256) void k_scanC(const unsigned short* __restrict__ dlt,
                                               const unsigned short* __restrict__ xm,
                                               const float* __restrict__ Bm,
                                               const float* __restrict__ Cm,
                                               const float* __restrict__ A_cl,
                                               const float* __restrict__ h_in,
                                               const float* __restrict__ Dvec,
                                               const unsigned short* __restrict__ gate,
                                               unsigned short* __restrict__ ymid) {
    const int d = blockIdx.x * 256 + threadIdx.x;
    const int c = blockIdx.y, b = blockIdx.z;
    __shared__ float Bsh[LCH][D_STATE];
    __shared__ float Csh[LCH][D_STATE];
    const int rowbase = b * LL + c * LCH;
    for (int i = threadIdx.x; i < LCH * D_STATE; i += 256) {
        ((float*)Bsh)[i] = Bm[(size_t)rowbase * D_STATE + i];
        ((float*)Csh)[i] = Cm[(size_t)rowbase * D_STATE + i];
    }
    __syncthreads();

    float Asv[16], h[16];
    const size_t coff = (((size_t)b * NCHUNK + c) * D_STATE) * D_MODEL + d;
    #pragma unroll
    for (int s = 0; s < 16; ++s) {
        Asv[s] = A_cl[s * D_MODEL + d];
        h[s] = h_in[coff + (size_t)s * D_MODEL];
    }
    const float Dv = Dvec[d];
    for (int tt = 0; tt < LCH; ++tt) {
        const size_t rowoff = (size_t)(rowbase + tt);
        float dltv = bf2f(dlt[rowoff * D_MODEL + d]);
        float xv   = bf2f(xm [rowoff * D_MODEL + d]);
        float dx = dltv * xv;
        float y = 0.f;
        #pragma unroll
        for (int s = 0; s < 16; ++s) {
            float dA  = __expf(fmaxf(dltv * Asv[s], -2.f));
            float dBu = clampf_(dx * Bsh[tt][s], -5.f, 5.f);
            h[s] = clampf_(fmaf(dA, h[s], dBu), -100.f, 100.f);
            y = fmaf(h[s], Csh[tt][s], y);
        }
        y = clampf_(y, -10.f, 10.f);
        y = fmaf(xv, Dv, y);
        y *= bf2f(gate[rowoff * D_MODEL + d]);
        ymid[rowoff * D_MODEL + d] = f2bf(y);
    }
}

// ---------------- launch ----------------
extern "C" void kernel_launch(void* const* d_in, const int* in_sizes, int n_in,
                              void* d_out, int out_size, void* d_ws, size_t ws_size,
                              hipStream_t stream) {
    const float* x       = (const float*)d_in[0];
    const float* W_in    = (const float*)d_in[1];
    const float* b_in    = (const float*)d_in[2];
    const float* W_B     = (const float*)d_in[3];
    const float* b_B     = (const float*)d_in[4];
    const float* W_C     = (const float*)d_in[5];
    const float* b_C     = (const float*)d_in[6];
    const float* W_delta = (const float*)d_in[7];
    const float* b_delta = (const float*)d_in[8];
    const float* W_out   = (const float*)d_in[9];
    const float* b_out   = (const float*)d_in[10];
    const float* A_log   = (const float*)d_in[11];
    const float* Dvec    = (const float*)d_in[12];
    float* out = (float*)d_out;

    char* p = (char*)d_ws;
    auto alloc = [&](size_t bytes) {
        char* r = p;
        p += (bytes + 255) & ~(size_t)255;
        return r;
    };
    unsigned short* Wint  = (unsigned short*)alloc((size_t)2 * D_MODEL * D_MODEL * 2);
    unsigned short* WdBC  = (unsigned short*)alloc((size_t)N_DBC * D_MODEL * 2);
    unsigned short* Wot   = (unsigned short*)alloc((size_t)D_MODEL * D_MODEL * 2);
    float*          bdbc  = (float*)alloc((size_t)N_DBC * 4);
    unsigned short* xm_b  = (unsigned short*)alloc((size_t)M_TOT * D_MODEL * 2);
    unsigned short* gate_b= (unsigned short*)alloc((size_t)M_TOT * D_MODEL * 2);
    unsigned short* dlt_b = (unsigned short*)alloc((size_t)M_TOT * D_MODEL * 2);
    float*          Bm    = (float*)alloc((size_t)M_TOT * D_STATE * 4);
    float*          Cm    = (float*)alloc((size_t)M_TOT * D_STATE * 4);
    float*          A_cl  = (float*)alloc((size_t)D_STATE * D_MODEL * 4);
    float*          h_end = (float*)alloc((size_t)BB * NCHUNK * D_STATE * D_MODEL * 4);
    float*          Aprod = (float*)alloc((size_t)BB * NCHUNK * D_STATE * D_MODEL * 4);
    float*          h_in  = (float*)alloc((size_t)BB * NCHUNK * D_STATE * D_MODEL * 4);
    unsigned short* ymid  = (unsigned short*)alloc((size_t)M_TOT * D_MODEL * 2);

    // prep (k_convert_x eliminated: gemm0 reads x as f32 and converts in-reg)
    k_prep_A<<<(D_STATE * D_MODEL + 255) / 256, 256, 0, stream>>>(A_log, A_cl, D_STATE * D_MODEL);
    k_transpose_bf16<<<dim3(2 * D_MODEL / 32, D_MODEL / 32), 256, 0, stream>>>(W_in, Wint, D_MODEL, 2 * D_MODEL);
    k_transpose_bf16<<<dim3(D_MODEL / 32, D_MODEL / 32), 256, 0, stream>>>(W_delta, WdBC, D_MODEL, D_MODEL);
    k_fill_bc<<<(128 * D_MODEL + 255) / 256, 256, 0, stream>>>(W_B, W_C, WdBC);
    k_bias_dbc<<<(N_DBC + 255) / 256, 256, 0, stream>>>(b_delta, b_B, b_C, bdbc);
    k_transpose_bf16<<<dim3(D_MODEL / 32, D_MODEL / 32), 256, 0, stream>>>(W_out, Wot, D_MODEL, D_MODEL);

    // in-proj GEMM + silu split; gx=12, 64x12 = 768 blocks (256 thr)
    k_gemm<0><<<dim3((2 * D_MODEL / 128) * (M_TOT / 128)), 256, 0, stream>>>(
        x, Wint, b_in, 2 * D_MODEL / 128, nullptr, nullptr, xm_b, gate_b);
    // delta + B + C fused GEMM; gx=7, 64x7 = 448 blocks
    k_gemm<1><<<dim3((N_DBC / 128) * (M_TOT / 128)), 256, 0, stream>>>(
        xm_b, WdBC, bdbc, N_DBC / 128, Bm, Cm, dlt_b, nullptr);
    // chunked scan
    k_scanA<<<dim3(D_MODEL / 256, NCHUNK, BB), 256, 0, stream>>>(dlt_b, xm_b, Bm, A_cl, h_end, Aprod);
    k_scanB<<<(BB * D_STATE * D_MODEL) / 256, 256, 0, stream>>>(h_end, Aprod, h_in);
    k_scanC<<<dim3(D_MODEL / 256, NCHUNK, BB), 256, 0, stream>>>(
        dlt_b, xm_b, Bm, Cm, A_cl, h_in, Dvec, gate_b, ymid);
    // out-proj GEMM + clip; gx=6, 64x6 = 384 blocks
    k_gemm<2><<<dim3((D_MODEL / 128) * (M_TOT / 128)), 256, 0, stream>>>(
        ymid, Wot, b_out, D_MODEL / 128, out, nullptr, nullptr, nullptr);
}

// Round 21
// 201.877 us; speedup vs baseline: 1.0812x; 1.0812x over previous
//
#include <hip/hip_runtime.h>
#include <hip/hip_bf16.h>
#include <cstdint>
#include <cstddef>

#define D_MODEL 768
#define D_STATE 16
#define BB      4
#define LL      2048
#define M_TOT   (BB*LL)      // 8192
#define NCHUNK  64
#define LCH     (LL/NCHUNK)  // 32
#define N_DBC   896          // 768 delta + 16 B + 16 C + 96 pad
#define KC      768          // all GEMMs share K = D_MODEL
#define BK      64           // k-elements per staged step
#define NT2     (KC/BK)      // 12 K-steps (even)

typedef __attribute__((ext_vector_type(8))) short bf16x8;
typedef __attribute__((ext_vector_type(4))) float f32x4;

__device__ __forceinline__ float clampf_(float x, float lo, float hi) {
    return fminf(fmaxf(x, lo), hi);
}
__device__ __forceinline__ float siluf_(float x) {
    return x / (1.f + __expf(-x));
}
// f32 -> bf16 round-to-nearest-even, as raw u16
__device__ __forceinline__ unsigned short f2bf(float f) {
    unsigned u = __float_as_uint(f);
    u += 0x7fffu + ((u >> 16) & 1u);
    return (unsigned short)(u >> 16);
}
__device__ __forceinline__ float bf2f(unsigned short u) {
    return __uint_as_float(((unsigned)u) << 16);
}

// ---------------- prep kernels ----------------

__global__ __launch_bounds__(256) void k_convert_x(const float* __restrict__ x,
                                                   unsigned short* __restrict__ xb, int n4) {
    int i = blockIdx.x * 256 + threadIdx.x;
    if (i >= n4) return;
    float4 v = ((const float4*)x)[i];
    ushort4 o;
    o.x = f2bf(v.x); o.y = f2bf(v.y); o.z = f2bf(v.z); o.w = f2bf(v.w);
    ((ushort4*)xb)[i] = o;
}

__global__ __launch_bounds__(256) void k_prep_A(const float* __restrict__ A_log,
                                                float* __restrict__ A_cl, int n) {
    int i = blockIdx.x * 256 + threadIdx.x;
    if (i < n) A_cl[i] = clampf_(-__expf(A_log[i]), -5.f, -0.1f);
}

// transpose R x C f32 -> C x R bf16 (R,C multiples of 32); dst row stride = R
__global__ __launch_bounds__(256) void k_transpose_bf16(const float* __restrict__ src,
                                                        unsigned short* __restrict__ dst,
                                                        int R, int C) {
    __shared__ float tile[32][33];
    int tx = threadIdx.x & 31, ty = threadIdx.x >> 5;
    int c0 = blockIdx.x * 32, r0 = blockIdx.y * 32;
    #pragma unroll
    for (int rr = ty; rr < 32; rr += 8)
        tile[rr][tx] = src[(size_t)(r0 + rr) * C + c0 + tx];
    __syncthreads();
    #pragma unroll
    for (int rr = ty; rr < 32; rr += 8)
        dst[(size_t)(c0 + rr) * R + r0 + tx] = f2bf(tile[tx][rr]);
}

// rows 768..895 of WdBC: W_B^T, W_C^T, zero-pad
__global__ __launch_bounds__(256) void k_fill_bc(const float* __restrict__ W_B,
                                                 const float* __restrict__ W_C,
                                                 unsigned short* __restrict__ WdBC) {
    int idx = blockIdx.x * 256 + threadIdx.x;     // 128*768
    if (idx >= 128 * D_MODEL) return;
    int r = idx / D_MODEL + D_MODEL, k = idx % D_MODEL;
    unsigned short v = 0;
    if (r < D_MODEL + 16)       v = f2bf(W_B[k * 16 + (r - D_MODEL)]);
    else if (r < D_MODEL + 32)  v = f2bf(W_C[k * 16 + (r - D_MODEL - 16)]);
    WdBC[(size_t)r * D_MODEL + k] = v;
}

__global__ __launch_bounds__(256) void k_bias_dbc(const float* __restrict__ b_delta,
                                                  const float* __restrict__ b_B,
                                                  const float* __restrict__ b_C,
                                                  float* __restrict__ bias) {
    int i = blockIdx.x * 256 + threadIdx.x;
    if (i >= N_DBC) return;
    float v = 0.f;
    if (i < D_MODEL)            v = b_delta[i];
    else if (i < D_MODEL + 16)  v = b_B[i - D_MODEL];
    else if (i < D_MODEL + 32)  v = b_C[i - D_MODEL - 16];
    bias[i] = v;
}

// ---------------- main bf16 MFMA GEMM ----------------
// 128x128 tile, 4 waves, BK=64 (12 K-steps), reg-staged, 2 LDS buffers
// (64KB), ONE barrier per K-step, XOR swizzle slot = jl ^ (row&7), named
// scalar staging (rule #20). Round-19 measured optimum: 50.8 us/GEMM.
template<int EPI>
__global__ __launch_bounds__(256, 2) void k_gemm(const unsigned short* __restrict__ A,
                                              const unsigned short* __restrict__ Bt,
                                              const float* __restrict__ bias,
                                              int gx,
                                              float* __restrict__ out_f,
                                              float* __restrict__ out_f2,
                                              unsigned short* __restrict__ out_b0,
                                              unsigned short* __restrict__ out_b1) {
    __shared__ __align__(16) unsigned short As0[128 * 64], As1[128 * 64];
    __shared__ __align__(16) unsigned short Bs0[128 * 64], Bs1[128 * 64];
    const int tid = threadIdx.x;
    const int wave = tid >> 6, lane = tid & 63;
    const int wm = wave >> 1, wn = wave & 1;
    const int lr = lane & 15;

    // bijective XCD swizzle (m204, r==0 case); all grids here are %8==0
    const int nwg = gridDim.x;
    const int wg = blockIdx.x;
    int swz = wg;
    if ((nwg & 7) == 0) {
        const int q = nwg >> 3;
        swz = (wg & 7) * q + (wg >> 3);
    }
    const int bx = swz % gx, by = swz / gx;
    const int m0 = by * 128, n0 = bx * 128;

    // staging: 128x64 tile = 1024 chunks of 8 shorts; thread owns chunks
    // c = g*256 + tid, g=0..3: row = c>>3, jl = c&7, slot = jl ^ (row&7).
    // All named scalars (no arrays -> no scratch demotion).
    const int row0 = tid >> 3, jl = tid & 7;
    const int r0_ = row0,      r1_ = row0 + 32,  r2_ = row0 + 64,  r3_ = row0 + 96;
    const unsigned short* gA0 = &A [(size_t)(m0 + r0_) * KC + jl * 8];
    const unsigned short* gA1 = &A [(size_t)(m0 + r1_) * KC + jl * 8];
    const unsigned short* gA2 = &A [(size_t)(m0 + r2_) * KC + jl * 8];
    const unsigned short* gA3 = &A [(size_t)(m0 + r3_) * KC + jl * 8];
    const unsigned short* gB0 = &Bt[(size_t)(n0 + r0_) * KC + jl * 8];
    const unsigned short* gB1 = &Bt[(size_t)(n0 + r1_) * KC + jl * 8];
    const unsigned short* gB2 = &Bt[(size_t)(n0 + r2_) * KC + jl * 8];
    const unsigned short* gB3 = &Bt[(size_t)(n0 + r3_) * KC + jl * 8];
    const int w0_ = r0_ * 64 + (jl ^ (r0_ & 7)) * 8;
    const int w1_ = r1_ * 64 + (jl ^ (r1_ & 7)) * 8;
    const int w2_ = r2_ * 64 + (jl ^ (r2_ & 7)) * 8;
    const int w3_ = r3_ * 64 + (jl ^ (r3_ & 7)) * 8;

    f32x4 acc[4][4] = {};
    float4 ra0, ra1, ra2, ra3, rb0, rb1, rb2, rb3;

    auto loadT = [&](int kt) {
        ra0 = *(const float4*)(gA0 + kt);
        ra1 = *(const float4*)(gA1 + kt);
        ra2 = *(const float4*)(gA2 + kt);
        ra3 = *(const float4*)(gA3 + kt);
        rb0 = *(const float4*)(gB0 + kt);
        rb1 = *(const float4*)(gB1 + kt);
        rb2 = *(const float4*)(gB2 + kt);
        rb3 = *(const float4*)(gB3 + kt);
    };
    auto writeT = [&](unsigned short* Ab, unsigned short* Bb) {
        *(float4*)&Ab[w0_] = ra0;
        *(float4*)&Ab[w1_] = ra1;
        *(float4*)&Ab[w2_] = ra2;
        *(float4*)&Ab[w3_] = ra3;
        *(float4*)&Bb[w0_] = rb0;
        *(float4*)&Bb[w1_] = rb1;
        *(float4*)&Bb[w2_] = rb2;
        *(float4*)&Bb[w3_] = rb3;
    };
    auto computeT = [&](const unsigned short* Ab, const unsigned short* Bb) {
        #pragma unroll
        for (int kh = 0; kh < 2; ++kh) {
            const int so = ((kh * 4 + (lane >> 4)) ^ (lr & 7)) * 8;  // swizzled k-slot
            bf16x8 af0 = *(const bf16x8*)&Ab[(wm * 64 +  0 + lr) * 64 + so];
            bf16x8 af1 = *(const bf16x8*)&Ab[(wm * 64 + 16 + lr) * 64 + so];
            bf16x8 af2 = *(const bf16x8*)&Ab[(wm * 64 + 32 + lr) * 64 + so];
            bf16x8 af3 = *(const bf16x8*)&Ab[(wm * 64 + 48 + lr) * 64 + so];
            bf16x8 bf0 = *(const bf16x8*)&Bb[(wn * 64 +  0 + lr) * 64 + so];
            bf16x8 bf1 = *(const bf16x8*)&Bb[(wn * 64 + 16 + lr) * 64 + so];
            bf16x8 bf2 = *(const bf16x8*)&Bb[(wn * 64 + 32 + lr) * 64 + so];
            bf16x8 bf3 = *(const bf16x8*)&Bb[(wn * 64 + 48 + lr) * 64 + so];
            acc[0][0] = __builtin_amdgcn_mfma_f32_16x16x32_bf16(af0, bf0, acc[0][0], 0, 0, 0);
            acc[0][1] = __builtin_amdgcn_mfma_f32_16x16x32_bf16(af0, bf1, acc[0][1], 0, 0, 0);
            acc[0][2] = __builtin_amdgcn_mfma_f32_16x16x32_bf16(af0, bf2, acc[0][2], 0, 0, 0);
            acc[0][3] = __builtin_amdgcn_mfma_f32_16x16x32_bf16(af0, bf3, acc[0][3], 0, 0, 0);
            acc[1][0] = __builtin_amdgcn_mfma_f32_16x16x32_bf16(af1, bf0, acc[1][0], 0, 0, 0);
            acc[1][1] = __builtin_amdgcn_mfma_f32_16x16x32_bf16(af1, bf1, acc[1][1], 0, 0, 0);
            acc[1][2] = __builtin_amdgcn_mfma_f32_16x16x32_bf16(af1, bf2, acc[1][2], 0, 0, 0);
            acc[1][3] = __builtin_amdgcn_mfma_f32_16x16x32_bf16(af1, bf3, acc[1][3], 0, 0, 0);
            acc[2][0] = __builtin_amdgcn_mfma_f32_16x16x32_bf16(af2, bf0, acc[2][0], 0, 0, 0);
            acc[2][1] = __builtin_amdgcn_mfma_f32_16x16x32_bf16(af2, bf1, acc[2][1], 0, 0, 0);
            acc[2][2] = __builtin_amdgcn_mfma_f32_16x16x32_bf16(af2, bf2, acc[2][2], 0, 0, 0);
            acc[2][3] = __builtin_amdgcn_mfma_f32_16x16x32_bf16(af2, bf3, acc[2][3], 0, 0, 0);
            acc[3][0] = __builtin_amdgcn_mfma_f32_16x16x32_bf16(af3, bf0, acc[3][0], 0, 0, 0);
            acc[3][1] = __builtin_amdgcn_mfma_f32_16x16x32_bf16(af3, bf1, acc[3][1], 0, 0, 0);
            acc[3][2] = __builtin_amdgcn_mfma_f32_16x16x32_bf16(af3, bf2, acc[3][2], 0, 0, 0);
            acc[3][3] = __builtin_amdgcn_mfma_f32_16x16x32_bf16(af3, bf3, acc[3][3], 0, 0, 0);
        }
    };

    // prologue: tiles 0 and 1 into buf0/buf1 (compiler inserts vmcnt waits)
    loadT(0);
    writeT(As0, Bs0);
    loadT(BK);
    writeT(As1, Bs1);
    asm volatile("s_waitcnt lgkmcnt(0)" ::: "memory");
    __builtin_amdgcn_sched_barrier(0);
    __builtin_amdgcn_s_barrier();
    __builtin_amdgcn_sched_barrier(0);

#define SUBSTEP(Ab, Bb, t) do {                                   \
        if ((t) + 2 < NT2) loadT(((t) + 2) * BK);                 \
        computeT(Ab, Bb);                                         \
        asm volatile("s_waitcnt lgkmcnt(0)" ::: "memory");        \
        __builtin_amdgcn_sched_barrier(0);                        \
        __builtin_amdgcn_s_barrier();                             \
        __builtin_amdgcn_sched_barrier(0);                        \
        if ((t) + 2 < NT2) writeT(Ab, Bb);                        \
    } while (0)

    for (int t = 0; t < NT2; t += 2) {
        SUBSTEP(As0, Bs0, t);
        SUBSTEP(As1, Bs1, t + 1);
    }
#undef SUBSTEP

    #pragma unroll
    for (int mt = 0; mt < 4; ++mt) {
        int row = m0 + wm * 64 + mt * 16 + (lane >> 4) * 4;
        #pragma unroll
        for (int nt = 0; nt < 4; ++nt) {
            int col = n0 + wn * 64 + nt * 16 + lr;
            #pragma unroll
            for (int i = 0; i < 4; ++i) {
                int r = row + i;
                float v = acc[mt][nt][i] + bias[col];
                if (EPI == 0) {
                    float s = siluf_(v);
                    if (col < D_MODEL) out_b0[(size_t)r * D_MODEL + col] = f2bf(s);
                    else               out_b1[(size_t)r * D_MODEL + (col - D_MODEL)] = f2bf(s);
                } else if (EPI == 1) {
                    if (col < D_MODEL) {
                        float sp = (v > 20.f) ? v : log1pf(__expf(v));
                        out_b0[(size_t)r * D_MODEL + col] = f2bf(clampf_(sp + 1e-4f, 1e-4f, 1.f));
                    } else if (col < D_MODEL + 16) {
                        out_f[(size_t)r * D_STATE + (col - D_MODEL)] = v;
                    } else if (col < D_MODEL + 32) {
                        out_f2[(size_t)r * D_STATE + (col - D_MODEL - 16)] = v;
                    }
                } else {
                    out_f[(size_t)r * D_MODEL + col] = clampf_(v, -10.f, 10.f);
                }
            }
        }
    }
}

// ---------------- chunked selective scan ----------------
// pass A: per (b, chunk, d) local scan from h=0; emit h_end, Aprod
__global__ __launch_bounds__(256) void k_scanA(const unsigned short* __restrict__ dlt,
                                               const unsigned short* __restrict__ xm,
                                               const float* __restrict__ Bm,
                                               const float* __restrict__ A_cl,
                                               float* __restrict__ h_end,
                                               float* __restrict__ Aprod) {
    const int d = blockIdx.x * 256 + threadIdx.x;
    const int c = blockIdx.y, b = blockIdx.z;
    __shared__ float Bsh[LCH][D_STATE];
    const int rowbase = b * LL + c * LCH;
    for (int i = threadIdx.x; i < LCH * D_STATE; i += 256)
        ((float*)Bsh)[i] = Bm[(size_t)rowbase * D_STATE + i];
    __syncthreads();

    float Asv[16], h[16], ap[16];
    #pragma unroll
    for (int s = 0; s < 16; ++s) {
        Asv[s] = A_cl[s * D_MODEL + d];
        h[s] = 0.f; ap[s] = 1.f;
    }
    for (int tt = 0; tt < LCH; ++tt) {
        const size_t rowoff = (size_t)(rowbase + tt);
        float dltv = bf2f(dlt[rowoff * D_MODEL + d]);
        float xv   = bf2f(xm [rowoff * D_MODEL + d]);
        float dx = dltv * xv;
        #pragma unroll
        for (int s = 0; s < 16; ++s) {
            float dA  = __expf(fmaxf(dltv * Asv[s], -2.f));
            float dBu = clampf_(dx * Bsh[tt][s], -5.f, 5.f);
            h[s] = clampf_(fmaf(dA, h[s], dBu), -100.f, 100.f);
            ap[s] *= dA;
        }
    }
    const size_t off = (((size_t)b * NCHUNK + c) * D_STATE) * D_MODEL + d;
    #pragma unroll
    for (int s = 0; s < 16; ++s) {
        h_end[off + (size_t)s * D_MODEL] = h[s];
        Aprod[off + (size_t)s * D_MODEL] = ap[s];
    }
}

// pass B: carry propagation across chunks per (b,s,d)
__global__ __launch_bounds__(256) void k_scanB(const float* __restrict__ h_end,
                                               const float* __restrict__ Aprod,
                                               float* __restrict__ h_in) {
    const int idx = blockIdx.x * 256 + threadIdx.x;  // 4*16*768 = 49152
    const int d = idx % D_MODEL;
    const int rest = idx / D_MODEL;
    const int s = rest & 15, b = rest >> 4;
    float hc = 0.f;
    for (int c = 0; c < NCHUNK; ++c) {
        const size_t off = (((size_t)b * NCHUNK + c) * D_STATE + s) * D_MODEL + d;
        h_in[off] = hc;
        hc = Aprod[off] * hc + h_end[off];
    }
}

// pass C: replay with true carry, fuse y = clip(sum_s h*C) + xm*D, * gate -> bf16
__global__ __launch_bounds__(256) void k_scanC(const unsigned short* __restrict__ dlt,
                                               const unsigned short* __restrict__ xm,
                                               const float* __restrict__ Bm,
                                               const float* __restrict__ Cm,
                                               const float* __restrict__ A_cl,
                                               const float* __restrict__ h_in,
                                               const float* __restrict__ Dvec,
                                               const unsigned short* __restrict__ gate,
                                               unsigned short* __restrict__ ymid) {
    const int d = blockIdx.x * 256 + threadIdx.x;
    const int c = blockIdx.y, b = blockIdx.z;
    __shared__ float Bsh[LCH][D_STATE];
    __shared__ float Csh[LCH][D_STATE];
    const int rowbase = b * LL + c * LCH;
    for (int i = threadIdx.x; i < LCH * D_STATE; i += 256) {
        ((float*)Bsh)[i] = Bm[(size_t)rowbase * D_STATE + i];
        ((float*)Csh)[i] = Cm[(size_t)rowbase * D_STATE + i];
    }
    __syncthreads();

    float Asv[16], h[16];
    const size_t coff = (((size_t)b * NCHUNK + c) * D_STATE) * D_MODEL + d;
    #pragma unroll
    for (int s = 0; s < 16; ++s) {
        Asv[s] = A_cl[s * D_MODEL + d];
        h[s] = h_in[coff + (size_t)s * D_MODEL];
    }
    const float Dv = Dvec[d];
    for (int tt = 0; tt < LCH; ++tt) {
        const size_t rowoff = (size_t)(rowbase + tt);
        float dltv = bf2f(dlt[rowoff * D_MODEL + d]);
        float xv   = bf2f(xm [rowoff * D_MODEL + d]);
        float dx = dltv * xv;
        float y = 0.f;
        #pragma unroll
        for (int s = 0; s < 16; ++s) {
            float dA  = __expf(fmaxf(dltv * Asv[s], -2.f));
            float dBu = clampf_(dx * Bsh[tt][s], -5.f, 5.f);
            h[s] = clampf_(fmaf(dA, h[s], dBu), -100.f, 100.f);
            y = fmaf(h[s], Csh[tt][s], y);
        }
        y = clampf_(y, -10.f, 10.f);
        y = fmaf(xv, Dv, y);
        y *= bf2f(gate[rowoff * D_MODEL + d]);
        ymid[rowoff * D_MODEL + d] = f2bf(y);
    }
}

// ---------------- launch ----------------
extern "C" void kernel_launch(void* const* d_in, const int* in_sizes, int n_in,
                              void* d_out, int out_size, void* d_ws, size_t ws_size,
                              hipStream_t stream) {
    const float* x       = (const float*)d_in[0];
    const float* W_in    = (const float*)d_in[1];
    const float* b_in    = (const float*)d_in[2];
    const float* W_B     = (const float*)d_in[3];
    const float* b_B     = (const float*)d_in[4];
    const float* W_C     = (const float*)d_in[5];
    const float* b_C     = (const float*)d_in[6];
    const float* W_delta = (const float*)d_in[7];
    const float* b_delta = (const float*)d_in[8];
    const float* W_out   = (const float*)d_in[9];
    const float* b_out   = (const float*)d_in[10];
    const float* A_log   = (const float*)d_in[11];
    const float* Dvec    = (const float*)d_in[12];
    float* out = (float*)d_out;

    char* p = (char*)d_ws;
    auto alloc = [&](size_t bytes) {
        char* r = p;
        p += (bytes + 255) & ~(size_t)255;
        return r;
    };
    unsigned short* xb    = (unsigned short*)alloc((size_t)M_TOT * D_MODEL * 2);
    unsigned short* Wint  = (unsigned short*)alloc((size_t)2 * D_MODEL * D_MODEL * 2);
    unsigned short* WdBC  = (unsigned short*)alloc((size_t)N_DBC * D_MODEL * 2);
    unsigned short* Wot   = (unsigned short*)alloc((size_t)D_MODEL * D_MODEL * 2);
    float*          bdbc  = (float*)alloc((size_t)N_DBC * 4);
    unsigned short* xm_b  = (unsigned short*)alloc((size_t)M_TOT * D_MODEL * 2);
    unsigned short* gate_b= (unsigned short*)alloc((size_t)M_TOT * D_MODEL * 2);
    unsigned short* dlt_b = (unsigned short*)alloc((size_t)M_TOT * D_MODEL * 2);
    float*          Bm    = (float*)alloc((size_t)M_TOT * D_STATE * 4);
    float*          Cm    = (float*)alloc((size_t)M_TOT * D_STATE * 4);
    float*          A_cl  = (float*)alloc((size_t)D_STATE * D_MODEL * 4);
    float*          h_end = (float*)alloc((size_t)BB * NCHUNK * D_STATE * D_MODEL * 4);
    float*          Aprod = (float*)alloc((size_t)BB * NCHUNK * D_STATE * D_MODEL * 4);
    float*          h_in  = (float*)alloc((size_t)BB * NCHUNK * D_STATE * D_MODEL * 4);
    unsigned short* ymid  = (unsigned short*)alloc((size_t)M_TOT * D_MODEL * 2);

    // prep
    k_convert_x<<<(M_TOT * D_MODEL / 4 + 255) / 256, 256, 0, stream>>>(x, xb, M_TOT * D_MODEL / 4);
    k_prep_A<<<(D_STATE * D_MODEL + 255) / 256, 256, 0, stream>>>(A_log, A_cl, D_STATE * D_MODEL);
    k_transpose_bf16<<<dim3(2 * D_MODEL / 32, D_MODEL / 32), 256, 0, stream>>>(W_in, Wint, D_MODEL, 2 * D_MODEL);
    k_transpose_bf16<<<dim3(D_MODEL / 32, D_MODEL / 32), 256, 0, stream>>>(W_delta, WdBC, D_MODEL, D_MODEL);
    k_fill_bc<<<(128 * D_MODEL + 255) / 256, 256, 0, stream>>>(W_B, W_C, WdBC);
    k_bias_dbc<<<(N_DBC + 255) / 256, 256, 0, stream>>>(b_delta, b_B, b_C, bdbc);
    k_transpose_bf16<<<dim3(D_MODEL / 32, D_MODEL / 32), 256, 0, stream>>>(W_out, Wot, D_MODEL, D_MODEL);

    // in-proj GEMM + silu split; gx=12, 64x12 = 768 blocks (256 thr)
    k_gemm<0><<<dim3((2 * D_MODEL / 128) * (M_TOT / 128)), 256, 0, stream>>>(
        xb, Wint, b_in, 2 * D_MODEL / 128, nullptr, nullptr, xm_b, gate_b);
    // delta + B + C fused GEMM; gx=7, 64x7 = 448 blocks
    k_gemm<1><<<dim3((N_DBC / 128) * (M_TOT / 128)), 256, 0, stream>>>(
        xm_b, WdBC, bdbc, N_DBC / 128, Bm, Cm, dlt_b, nullptr);
    // chunked scan
    k_scanA<<<dim3(D_MODEL / 256, NCHUNK, BB), 256, 0, stream>>>(dlt_b, xm_b, Bm, A_cl, h_end, Aprod);
    k_scanB<<<(BB * D_STATE * D_MODEL) / 256, 256, 0, stream>>>(h_end, Aprod, h_in);
    k_scanC<<<dim3(D_MODEL / 256, NCHUNK, BB), 256, 0, stream>>>(
        dlt_b, xm_b, Bm, Cm, A_cl, h_in, Dvec, gate_b, ymid);
    // out-proj GEMM + clip; gx=6, 64x6 = 384 blocks
    k_gemm<2><<<dim3((D_MODEL / 128) * (M_TOT / 128)), 256, 0, stream>>>(
        ymid, Wot, b_out, D_MODEL / 128, out, nullptr, nullptr, nullptr);
}